// Round 3
// baseline (1720.885 us; speedup 1.0000x reference)
//
#include <hip/hip_runtime.h>
#include <hip/hip_bf16.h>

using bf16x8 = __attribute__((ext_vector_type(8))) short;
using f32x4  = __attribute__((ext_vector_type(4))) float;
using f16x2  = __attribute__((ext_vector_type(2))) _Float16;

#define ODE_NSTEP 32  // RK4 x32 validated in round 2 (absmax unchanged vs fp32 RK45x49)

__device__ __forceinline__ unsigned short f2bf(float f) {
    unsigned int u = __float_as_uint(f);
    return (unsigned short)((u + 0x7fffu + ((u >> 16) & 1u)) >> 16);
}
__device__ __forceinline__ unsigned short f2h(float f) {
    _Float16 h = (_Float16)f;
    return __builtin_bit_cast(unsigned short, h);
}
__device__ __forceinline__ unsigned int packh(float lo, float hi) {
    return (unsigned int)f2h(lo) | ((unsigned int)f2h(hi) << 16);
}

__device__ __forceinline__ float fdot2u(unsigned int a, unsigned int b, float c) {
#if __has_builtin(__builtin_amdgcn_fdot2)
    return __builtin_amdgcn_fdot2(__builtin_bit_cast(f16x2, a),
                                  __builtin_bit_cast(f16x2, b), c, false);
#else
    f16x2 av = __builtin_bit_cast(f16x2, a), bv = __builtin_bit_cast(f16x2, b);
    return c + (float)av.x * (float)bv.x + (float)av.y * (float)bv.y;
#endif
}

__device__ __forceinline__ float fast_tanh(float xx) {
    float a = __expf(-2.f * fabsf(xx));
    float r = (1.f - a) / (1.f + a);
    return copysignf(r, xx);
}

// ---------------------------------------------------------------------------
// K0: weight repack.
//  trunk: tW2T/tW3T bf16 [col][k]
//  branch (f16 pairs along k):
//   W1p u32[64kp][256c]; W2r u32[32j][512c][4q] (uint4/col, k=8j+2q,+1)
//   W3s u32[256kp][64g][4q] (uint4: cols 4g..4g+3 of pair kp)
//   W4p u32[128kp][128c]
// ---------------------------------------------------------------------------
__global__ void convert_kernel(const float* __restrict__ tW2, const float* __restrict__ tW3,
                               const float* __restrict__ bW1, const float* __restrict__ bW2,
                               const float* __restrict__ bW3, const float* __restrict__ bW4,
                               unsigned short* __restrict__ tW2T, unsigned short* __restrict__ tW3T,
                               unsigned int* __restrict__ W1p, unsigned int* __restrict__ W2r,
                               unsigned int* __restrict__ W3s, unsigned int* __restrict__ W4p) {
    int idx = blockIdx.x * blockDim.x + threadIdx.x;
    if (idx < 262144) {
        int col = idx >> 9, k = idx & 511;
        tW2T[idx] = f2bf(tW2[k * 512 + col]);
    } else if (idx < 327680) {
        int i = idx - 262144, col = i >> 9, k = i & 511;
        tW3T[i] = f2bf(tW3[k * 128 + col]);
    } else if (idx < 344064) {
        int i = idx - 327680, kp = i >> 8, c = i & 255;
        W1p[i] = packh(bW1[(2 * kp) * 256 + c], bW1[(2 * kp + 1) * 256 + c]);
    } else if (idx < 409600) {
        int i = idx - 344064, j = i >> 11, rem = i & 2047, c = rem >> 2, q = rem & 3;
        W2r[i] = packh(bW2[(8 * j + 2 * q) * 512 + c], bW2[(8 * j + 2 * q + 1) * 512 + c]);
    } else if (idx < 475136) {
        int i = idx - 409600, kp = i >> 8, rem = i & 255, g = rem >> 2, q = rem & 3;
        int c = 4 * g + q;
        W3s[i] = packh(bW3[(2 * kp) * 256 + c], bW3[(2 * kp + 1) * 256 + c]);
    } else if (idx < 491520) {
        int i = idx - 475136, kp = i >> 7, c = i & 127;
        W4p[i] = packh(bW4[(2 * kp) * 128 + c], bW4[(2 * kp + 1) * 128 + c]);
    }
}

// ---------------------------------------------------------------------------
// K1: ODE branch. 64 WGs x 512 thr. f16 dot2 everywhere, f32 accumulate.
// W2 in registers (128 VGPR/thread); W1/W4 LDS-resident; W3 streamed coalesced.
// Activation broadcast via ds_read_b32 + v_readlane.
// ---------------------------------------------------------------------------
extern __shared__ char ode_smem[];

#define RL(v, l) __builtin_amdgcn_readlane((v), (l))

__global__ __launch_bounds__(512, 2) void ode_kernel(
    const float* __restrict__ x0,
    const unsigned int* __restrict__ gW1p, const float* __restrict__ bb1,
    const unsigned int* __restrict__ gW2r, const float* __restrict__ bb2,
    const unsigned int* __restrict__ gW3s, const float* __restrict__ bb3,
    const unsigned int* __restrict__ gW4p, const float* __restrict__ bb4,
    float* __restrict__ branch) {
    unsigned int* w1 = (unsigned int*)ode_smem;             // 64 KB  [64kp][256c]
    unsigned int* w4 = (unsigned int*)(ode_smem + 65536);   // 64 KB  [128kp][128c]
    float* part = (float*)(ode_smem + 131072);              // 8 KB
    unsigned short* vh  = (unsigned short*)(ode_smem + 139264);  // 128 f16
    unsigned short* h1h = (unsigned short*)(ode_smem + 139520);  // 256 f16
    unsigned short* h2h = (unsigned short*)(ode_smem + 140032);  // 512 f16
    unsigned short* h3h = (unsigned short*)(ode_smem + 141056);  // 256 f16

    const unsigned int* vq  = (const unsigned int*)vh;
    const unsigned int* h1q = (const unsigned int*)h1h;
    const unsigned int* h2q = (const unsigned int*)h2h;
    const unsigned int* h3q = (const unsigned int*)h3h;

    const int t = threadIdx.x;
    const int lane = t & 63;

    // stage LDS-resident weights (coalesced uint4)
    {
        uint4* d1 = (uint4*)w1; const uint4* s1 = (const uint4*)gW1p;
#pragma unroll
        for (int i = 0; i < 8; ++i) d1[t + i * 512] = s1[t + i * 512];
        uint4* d4 = (uint4*)w4; const uint4* s4 = (const uint4*)gW4p;
#pragma unroll
        for (int i = 0; i < 8; ++i) d4[t + i * 512] = s4[t + i * 512];
    }
    // W2 -> registers: thread t owns column t (all 256 k as 128 pairs)
    uint4 w2r[32];
    {
        const uint4* s2 = (const uint4*)gW2r;
#pragma unroll
        for (int j = 0; j < 32; ++j) w2r[j] = s2[j * 512 + t];
    }
    // biases / state to registers
    float b1r = (t < 256) ? bb1[t] : 0.f;
    float b2r = bb2[t];
    float b3r = (t < 256) ? bb3[t] : 0.f;
    float b4r = (t < 128) ? bb4[t] : 0.f;
    float x_reg = 0.f, xa_reg = 0.f;
    if (t < 128) {
        x_reg = x0[blockIdx.x * 128 + t];
        xa_reg = x_reg;
        vh[t] = f2h(x_reg);
    }
    __syncthreads();

    const float dt = 1.0f / (float)ODE_NSTEP;
    const int khA = t >> 8;            // L1 k-half (wave-uniform)
    const int jA  = t & 255;
    const int gC  = t & 63;            // L3 col-group
    const int kqC = t >> 6;            // L3 k-eighth (== wave id)
    const int jD  = t & 127;
    const int kqD = t >> 7;            // L4 k-quarter (wave-uniform)

    for (int step = 0; step < ODE_NSTEP; ++step) {
        for (int s = 0; s < 4; ++s) {
            // ---- L1: v[128] -> h1[256] (W1 in LDS, acts via readlane) ----
            {
                unsigned int vr = vq[lane];  // 64 pairs total; lane l holds pair l
                const int kb = khA * 32;
                float a0 = 0.f, a1 = 0.f;
#pragma unroll
                for (int i = 0; i < 32; i += 2) {
                    unsigned int h0 = RL(vr, kb + i);
                    unsigned int h1v = RL(vr, kb + i + 1);
                    a0 = fdot2u(h0, w1[(kb + i) * 256 + jA], a0);
                    a1 = fdot2u(h1v, w1[(kb + i + 1) * 256 + jA], a1);
                }
                part[khA * 256 + jA] = a0 + a1;
            }
            __syncthreads();
            if (t < 256) h1h[t] = f2h(fast_tanh(part[t] + part[256 + t] + b1r));
            __syncthreads();
            // ---- L2: h1[256] -> h2[512] (W2 in registers, full K per thread) ----
            {
                unsigned int h1r0 = h1q[lane], h1r1 = h1q[64 + lane];  // 128 pairs
                float a0 = b2r, a1 = 0.f, a2 = 0.f, a3 = 0.f;
#pragma unroll
                for (int j = 0; j < 32; ++j) {
                    uint4 wv = w2r[j];
                    {
                        const int m = 4 * j;
                        unsigned int hp = RL((m < 64) ? h1r0 : h1r1, m & 63);
                        a0 = fdot2u(hp, wv.x, a0);
                    }
                    {
                        const int m = 4 * j + 1;
                        unsigned int hp = RL((m < 64) ? h1r0 : h1r1, m & 63);
                        a1 = fdot2u(hp, wv.y, a1);
                    }
                    {
                        const int m = 4 * j + 2;
                        unsigned int hp = RL((m < 64) ? h1r0 : h1r1, m & 63);
                        a2 = fdot2u(hp, wv.z, a2);
                    }
                    {
                        const int m = 4 * j + 3;
                        unsigned int hp = RL((m < 64) ? h1r0 : h1r1, m & 63);
                        a3 = fdot2u(hp, wv.w, a3);
                    }
                }
                h2h[t] = f2h(fast_tanh((a0 + a1) + (a2 + a3)));
            }
            __syncthreads();
            // ---- L3: h2[512] -> h3[256] (W3 streamed coalesced, split-K 8) ----
            {
                unsigned int h2r0 = h2q[lane], h2r1 = h2q[64 + lane];
                unsigned int h2r2 = h2q[128 + lane], h2r3 = h2q[192 + lane];
                unsigned int hsel_lo = (kqC & 2) ? h2r2 : h2r0;   // reg = kq>>1
                unsigned int hsel_hi = (kqC & 2) ? h2r3 : h2r1;
                unsigned int hsel = (kqC & 4) ? ((kqC & 2) ? h2r3 : h2r2)
                                              : ((kqC & 2) ? h2r1 : h2r0);
                // note: reg index = kq>>1 in {0,1,2,3}
                hsel = ((kqC >> 1) == 0) ? h2r0 : ((kqC >> 1) == 1) ? h2r1
                       : ((kqC >> 1) == 2) ? h2r2 : h2r3;
                (void)hsel_lo; (void)hsel_hi;
                const int lbase = (kqC & 1) * 32;
                const uint4* wp = (const uint4*)gW3s + kqC * 32 * 64 + gC;
                float a0 = 0.f, a1 = 0.f, a2 = 0.f, a3 = 0.f;
#pragma unroll
                for (int i = 0; i < 32; ++i) {
                    uint4 wv = wp[i * 64];
                    unsigned int hp = RL(hsel, lbase + i);
                    a0 = fdot2u(hp, wv.x, a0);
                    a1 = fdot2u(hp, wv.y, a1);
                    a2 = fdot2u(hp, wv.z, a2);
                    a3 = fdot2u(hp, wv.w, a3);
                }
                *(f32x4*)(part + kqC * 256 + gC * 4) = (f32x4){a0, a1, a2, a3};
            }
            __syncthreads();
            if (t < 256) {
                float z = b3r;
#pragma unroll
                for (int q = 0; q < 8; ++q) z += part[q * 256 + t];
                h3h[t] = f2h(fast_tanh(z));
            }
            __syncthreads();
            // ---- L4: h3[256] -> k[128] (W4 in LDS, split-K 4) ----
            {
                unsigned int h3r0 = h3q[lane], h3r1 = h3q[64 + lane];
                unsigned int hsel = (kqD & 2) ? h3r1 : h3r0;  // reg = kq>>1
                const int lbase = (kqD & 1) * 32;
                const int kb = kqD * 32;
                float a0 = 0.f, a1 = 0.f;
#pragma unroll
                for (int i = 0; i < 32; i += 2) {
                    unsigned int h0 = RL(hsel, lbase + i);
                    unsigned int h1v = RL(hsel, lbase + i + 1);
                    a0 = fdot2u(h0, w4[(kb + i) * 128 + jD], a0);
                    a1 = fdot2u(h1v, w4[(kb + i + 1) * 128 + jD], a1);
                }
                part[kqD * 128 + jD] = a0 + a1;
            }
            __syncthreads();
            if (t < 128) {
                float kk = part[t] + part[128 + t] + part[256 + t] + part[384 + t] + b4r;
                float wB = (s == 0 || s == 3) ? dt * (1.f / 6.f) : dt * (1.f / 3.f);
                xa_reg += wB * kk;
                float vnew;
                if (s < 3) vnew = x_reg + ((s == 2) ? dt : 0.5f * dt) * kk;
                else       { x_reg = xa_reg; vnew = xa_reg; }
                vh[t] = f2h(vnew);
            }
            __syncthreads();
        }
    }
    if (t < 128) branch[blockIdx.x * 128 + t] = x_reg;
}

// ---------------------------------------------------------------------------
// K2: fused trunk + combine. M=64 rows/WG, 1024 thr (16 waves), 4x B-reuse.
// ---------------------------------------------------------------------------
__device__ __forceinline__ int swz(int row, int byte_in_row) {
    return (row * 1024 + byte_in_row) ^ ((row & 7) << 4);
}

extern __shared__ char tk_smem[];

__global__ __launch_bounds__(1024, 4) void trunk_kernel(
    const float* __restrict__ coords,
    const float* __restrict__ tW1, const float* __restrict__ tb1,
    const unsigned short* __restrict__ tW2T, const float* __restrict__ tb2,
    const unsigned short* __restrict__ tW3T, const float* __restrict__ tb3,
    const float* __restrict__ oW, const float* __restrict__ ob,
    const float* __restrict__ branch, float* __restrict__ out) {
    // LDS: h1 bf16[64][512] swz @0 (64K); h2 bf16 @65536 (64K);
    //      h3 f32[64][132] @65536 after L3 overwrites h2? NO: h3 @65536 reuses h2
    //      only AFTER L3 reads finish -> instead h3 goes to @0 (h1 dead after L2).
    //      coords f32[256] @131072; bw f32[128] @132096.
    const int t = threadIdx.x;
    const int blk = blockIdx.x;
    const int b = blk >> 5;
    const int p0 = (blk & 31) * 64;

    float* coordsLds = (float*)(tk_smem + 131072);
    float* bwp = (float*)(tk_smem + 132096);
    if (t < 256) coordsLds[t] = coords[(b * 2048 + p0) * 4 + t];
    else if (t < 384) bwp[t - 256] = branch[b * 128 + (t - 256)] * oW[t - 256];
    __syncthreads();

    // ---- L1: h1[64][512] = relu(coords @ tW1 + tb1) -> bf16 swizzled @0 ----
    {
        const int r = t & 63, cs = t >> 6;
        const float c0 = coordsLds[r * 4 + 0], c1 = coordsLds[r * 4 + 1];
        const float c2 = coordsLds[r * 4 + 2], c3 = coordsLds[r * 4 + 3];
#pragma unroll
        for (int i = 0; i < 32; i += 2) {
            int c = cs * 32 + i;
            float v0 = fmaxf(c0 * tW1[c] + c1 * tW1[512 + c] + c2 * tW1[1024 + c] +
                                 c3 * tW1[1536 + c] + tb1[c], 0.f);
            float v1 = fmaxf(c0 * tW1[c + 1] + c1 * tW1[512 + c + 1] + c2 * tW1[1024 + c + 1] +
                                 c3 * tW1[1536 + c + 1] + tb1[c + 1], 0.f);
            *(unsigned int*)(tk_smem + swz(r, c * 2)) =
                (unsigned int)f2bf(v0) | ((unsigned int)f2bf(v1) << 16);
        }
    }
    __syncthreads();

    const int w = t >> 6, l = t & 63;
    const int lrow = l & 15, lk8 = (l >> 4) * 8;

    // ---- L2: h2[64][512] = relu(h1 @ tW2 + tb2); wave w: cols w*32..+31, 4 row-tiles ----
    {
        const int colbase = w * 32;
        f32x4 acc[4][2];
#pragma unroll
        for (int nt = 0; nt < 2; ++nt) {
            float bias = tb2[colbase + nt * 16 + lrow];
#pragma unroll
            for (int rt = 0; rt < 4; ++rt) acc[rt][nt] = (f32x4){bias, bias, bias, bias};
        }
        for (int ksI = 0; ksI < 16; ++ksI) {
            int kb = ksI * 32 + lk8;
            bf16x8 af[4];
#pragma unroll
            for (int rt = 0; rt < 4; ++rt)
                af[rt] = *(const bf16x8*)(tk_smem + swz(rt * 16 + lrow, kb * 2));
#pragma unroll
            for (int nt = 0; nt < 2; ++nt) {
                bf16x8 bfr = *(const bf16x8*)(tW2T + (colbase + nt * 16 + lrow) * 512 + kb);
#pragma unroll
                for (int rt = 0; rt < 4; ++rt)
                    acc[rt][nt] = __builtin_amdgcn_mfma_f32_16x16x32_bf16(af[rt], bfr, acc[rt][nt], 0, 0, 0);
            }
        }
#pragma unroll
        for (int nt = 0; nt < 2; ++nt) {
            int col = colbase + nt * 16 + lrow;
#pragma unroll
            for (int rt = 0; rt < 4; ++rt)
#pragma unroll
                for (int i = 0; i < 4; ++i) {
                    int rw = rt * 16 + (l >> 4) * 4 + i;
                    *(unsigned short*)(tk_smem + 65536 + swz(rw, col * 2)) =
                        f2bf(fmaxf(acc[rt][nt][i], 0.f));
                }
        }
    }
    __syncthreads();

    // ---- L3: h3[64][128] = relu(h2 @ tW3 + tb3) -> f32 @0 (h1 dead) ----
    {
        float* h3p = (float*)tk_smem;
        if (w < 8) {
            const int colbase = w * 16;
            f32x4 acc3[4];
            float bias = tb3[colbase + lrow];
#pragma unroll
            for (int rt = 0; rt < 4; ++rt) acc3[rt] = (f32x4){bias, bias, bias, bias};
            for (int ksI = 0; ksI < 16; ++ksI) {
                int kb = ksI * 32 + lk8;
                bf16x8 bfr = *(const bf16x8*)(tW3T + (colbase + lrow) * 512 + kb);
#pragma unroll
                for (int rt = 0; rt < 4; ++rt) {
                    bf16x8 af = *(const bf16x8*)(tk_smem + 65536 + swz(rt * 16 + lrow, kb * 2));
                    acc3[rt] = __builtin_amdgcn_mfma_f32_16x16x32_bf16(af, bfr, acc3[rt], 0, 0, 0);
                }
            }
            __syncthreads();  // all waves: h1 region reads done before h3 overwrite
#pragma unroll
            for (int rt = 0; rt < 4; ++rt)
#pragma unroll
                for (int i = 0; i < 4; ++i) {
                    int rw = rt * 16 + (l >> 4) * 4 + i;
                    h3p[rw * 132 + colbase + lrow] = fmaxf(acc3[rt][i], 0.f);
                }
        } else {
            __syncthreads();
        }
    }
    __syncthreads();

    // ---- combine: out[p] = sum_d h3[p][d]*bw[d] + ob ----
    {
        const float* h3p = (const float*)tk_smem;
        const int p = t >> 4, seg = t & 15;
        float s = 0.f;
#pragma unroll
        for (int i = 0; i < 8; ++i) {
            int d = seg * 8 + i;
            s += h3p[p * 132 + d] * bwp[d];
        }
        s += __shfl_down(s, 8, 16);
        s += __shfl_down(s, 4, 16);
        s += __shfl_down(s, 2, 16);
        s += __shfl_down(s, 1, 16);
        if (seg == 0) out[b * 2048 + p0 + p] = s + ob[0];
    }
}

// ---------------------------------------------------------------------------
extern "C" void kernel_launch(void* const* d_in, const int* in_sizes, int n_in,
                              void* d_out, int out_size, void* d_ws, size_t ws_size,
                              hipStream_t stream) {
    const float* parameter = (const float*)d_in[0];
    const float* coords    = (const float*)d_in[1];
    const float* bW1 = (const float*)d_in[2];  const float* bb1 = (const float*)d_in[3];
    const float* bW2 = (const float*)d_in[4];  const float* bb2 = (const float*)d_in[5];
    const float* bW3 = (const float*)d_in[6];  const float* bb3 = (const float*)d_in[7];
    const float* bW4 = (const float*)d_in[8];  const float* bb4 = (const float*)d_in[9];
    const float* tW1 = (const float*)d_in[10]; const float* tb1 = (const float*)d_in[11];
    const float* tW2 = (const float*)d_in[12]; const float* tb2 = (const float*)d_in[13];
    const float* tW3 = (const float*)d_in[14]; const float* tb3 = (const float*)d_in[15];
    const float* oW  = (const float*)d_in[16]; const float* ob  = (const float*)d_in[17];

    char* ws = (char*)d_ws;
    unsigned short* tW2T = (unsigned short*)(ws);             // 524288
    unsigned short* tW3T = (unsigned short*)(ws + 524288);    // 131072
    unsigned int*   W1p  = (unsigned int*)(ws + 655360);      // 65536
    unsigned int*   W2r  = (unsigned int*)(ws + 720896);      // 262144
    unsigned int*   W3s  = (unsigned int*)(ws + 983040);      // 262144
    unsigned int*   W4p  = (unsigned int*)(ws + 1245184);     // 65536
    float* branch        = (float*)(ws + 1310720);            // 32768
    float* out = (float*)d_out;

    hipLaunchKernelGGL(convert_kernel, dim3(1920), dim3(256), 0, stream,
                       tW2, tW3, bW1, bW2, bW3, bW4,
                       tW2T, tW3T, W1p, W2r, W3s, W4p);

    hipFuncSetAttribute(reinterpret_cast<const void*>(&ode_kernel),
                        hipFuncAttributeMaxDynamicSharedMemorySize, 141568);
    hipLaunchKernelGGL(ode_kernel, dim3(64), dim3(512), 141568, stream,
                       parameter, W1p, bb1, W2r, bb2, W3s, bb3, W4p, bb4, branch);

    hipFuncSetAttribute(reinterpret_cast<const void*>(&trunk_kernel),
                        hipFuncAttributeMaxDynamicSharedMemorySize, 132608);
    hipLaunchKernelGGL(trunk_kernel, dim3(2048), dim3(1024), 132608, stream,
                       coords, tW1, tb1, tW2T, tb2, tW3T, tb3, oW, ob, branch, out);
}

// Round 4
// 991.323 us; speedup vs baseline: 1.7359x; 1.7359x over previous
//
#include <hip/hip_runtime.h>
#include <hip/hip_bf16.h>

using bf16x8 = __attribute__((ext_vector_type(8))) short;
using f32x4  = __attribute__((ext_vector_type(4))) float;
using f16x2  = __attribute__((ext_vector_type(2))) _Float16;

#define ODE_NSTEP 32  // RK4 x32 validated (absmax identical to fp32 RK45x49)

__device__ __forceinline__ unsigned short f2bf(float f) {
    unsigned int u = __float_as_uint(f);
    return (unsigned short)((u + 0x7fffu + ((u >> 16) & 1u)) >> 16);
}
__device__ __forceinline__ unsigned short f2h(float f) {
    _Float16 h = (_Float16)f;
    return __builtin_bit_cast(unsigned short, h);
}
__device__ __forceinline__ unsigned int packh(float lo, float hi) {
    return (unsigned int)f2h(lo) | ((unsigned int)f2h(hi) << 16);
}
__device__ __forceinline__ float fdot2u(unsigned int a, unsigned int b, float c) {
#if __has_builtin(__builtin_amdgcn_fdot2)
    return __builtin_amdgcn_fdot2(__builtin_bit_cast(f16x2, a),
                                  __builtin_bit_cast(f16x2, b), c, false);
#else
    f16x2 av = __builtin_bit_cast(f16x2, a), bv = __builtin_bit_cast(f16x2, b);
    return c + (float)av.x * (float)bv.x + (float)av.y * (float)bv.y;
#endif
}
__device__ __forceinline__ float fast_tanh(float xx) {
    float a = __expf(-2.f * fabsf(xx));
    float r = (1.f - a) / (1.f + a);
    return copysignf(r, xx);
}

// ---------------------------------------------------------------------------
// K0: weight repack.
//  trunk: tW2T/tW3T bf16 [col][k]
//  branch f16 k-pairs, [kp][col] u32:
//   W1u [64][256]  W2u [128][512]  W3u [256][256]  W4u [128][128]
// ---------------------------------------------------------------------------
__global__ void convert_kernel(const float* __restrict__ tW2, const float* __restrict__ tW3,
                               const float* __restrict__ bW1, const float* __restrict__ bW2,
                               const float* __restrict__ bW3, const float* __restrict__ bW4,
                               unsigned short* __restrict__ tW2T, unsigned short* __restrict__ tW3T,
                               unsigned int* __restrict__ W1u, unsigned int* __restrict__ W2u,
                               unsigned int* __restrict__ W3u, unsigned int* __restrict__ W4u) {
    int idx = blockIdx.x * blockDim.x + threadIdx.x;
    if (idx < 262144) {
        int col = idx >> 9, k = idx & 511;
        tW2T[idx] = f2bf(tW2[k * 512 + col]);
    } else if (idx < 327680) {
        int i = idx - 262144, col = i >> 9, k = i & 511;
        tW3T[i] = f2bf(tW3[k * 128 + col]);
    } else if (idx < 344064) {
        int i = idx - 327680, kp = i >> 8, c = i & 255;
        W1u[i] = packh(bW1[(2 * kp) * 256 + c], bW1[(2 * kp + 1) * 256 + c]);
    } else if (idx < 409600) {
        int i = idx - 344064, kp = i >> 9, c = i & 511;
        W2u[i] = packh(bW2[(2 * kp) * 512 + c], bW2[(2 * kp + 1) * 512 + c]);
    } else if (idx < 475136) {
        int i = idx - 409600, kp = i >> 8, c = i & 255;
        W3u[i] = packh(bW3[(2 * kp) * 256 + c], bW3[(2 * kp + 1) * 256 + c]);
    } else if (idx < 491520) {
        int i = idx - 475136, kp = i >> 7, c = i & 127;
        W4u[i] = packh(bW4[(2 * kp) * 128 + c], bW4[(2 * kp + 1) * 128 + c]);
    }
}

// ---------------------------------------------------------------------------
// K1: ODE branch, RK4 x 32. 64 WGs x 512 thr. f16 dot2, f32 accumulate.
// W1/W4 LDS-resident; W2/W3 streamed coalesced dwordx4 with reg prefetch.
// Activation pairs broadcast via wave-uniform ds_read_b128 (no readlane).
// ---------------------------------------------------------------------------
extern __shared__ char ode_smem[];

__global__ __launch_bounds__(512, 2) void ode_kernel(
    const float* __restrict__ x0,
    const unsigned int* __restrict__ gW1, const float* __restrict__ bb1,
    const unsigned int* __restrict__ gW2, const float* __restrict__ bb2,
    const unsigned int* __restrict__ gW3, const float* __restrict__ bb3,
    const unsigned int* __restrict__ gW4, const float* __restrict__ bb4,
    float* __restrict__ branch) {
    unsigned int* w1  = (unsigned int*)ode_smem;             // [64][256]  64 KB
    unsigned int* w4  = (unsigned int*)(ode_smem + 65536);   // [128][128] 64 KB
    float*        part = (float*)(ode_smem + 131072);        // 16 KB
    unsigned int* vq  = (unsigned int*)(ode_smem + 147456);  // 64 u32
    unsigned int* h1q = (unsigned int*)(ode_smem + 147712);  // 128 u32
    unsigned int* h2q = (unsigned int*)(ode_smem + 148224);  // 256 u32
    unsigned int* h3q = (unsigned int*)(ode_smem + 149248);  // 128 u32

    const int t = threadIdx.x;
    const int lane = t & 63, wave = t >> 6;
    const int kq16 = t >> 5, g32 = t & 31;

    {   // stage resident weights
        const uint4* s1 = (const uint4*)gW1; uint4* d1 = (uint4*)w1;
#pragma unroll
        for (int i = 0; i < 8; ++i) d1[t + i * 512] = s1[t + i * 512];
        const uint4* s4 = (const uint4*)gW4; uint4* d4 = (uint4*)w4;
#pragma unroll
        for (int i = 0; i < 8; ++i) d4[t + i * 512] = s4[t + i * 512];
    }
    float2 b1p = make_float2(0.f, 0.f), b2p = b1p, b3p = b1p, b4p = b1p;
    if (t < 128) b1p = ((const float2*)bb1)[t];
    if (t < 256) b2p = ((const float2*)bb2)[t];
    if (t < 128) b3p = ((const float2*)bb3)[t];
    if (t < 64)  b4p = ((const float2*)bb4)[t];
    float xs0 = 0.f, xs1 = 0.f, xa0 = 0.f, xa1 = 0.f;
    if (t < 64) {
        float2 xv = ((const float2*)x0)[blockIdx.x * 64 + t];
        xs0 = xv.x; xs1 = xv.y; xa0 = xs0; xa1 = xs1;
        vq[t] = packh(xs0, xs1);
    }
    __syncthreads();

    const float dt = 1.0f / (float)ODE_NSTEP;
    const uint4* vq4  = (const uint4*)vq;
    const uint4* h1q4 = (const uint4*)h1q;
    const uint4* h2q4 = (const uint4*)h2q;
    const uint4* h3q4 = (const uint4*)h3q;
    const uint4* w1q = (const uint4*)w1;
    const uint4* w4q = (const uint4*)w4;
    const uint4* g2q = (const uint4*)gW2;
    const uint4* g3q = (const uint4*)gW3;

    for (int it = 0; it < ODE_NSTEP * 4; ++it) {
        const int s = it & 3;
        // ---- L1: v(64kp) -> h1(256c). W1 LDS. wave=k-slice, lane=4 cols ----
        {
            uint4 va = vq4[wave * 2], vb = vq4[wave * 2 + 1];
            unsigned int hp[8] = {va.x, va.y, va.z, va.w, vb.x, vb.y, vb.z, vb.w};
            float a0 = 0.f, a1 = 0.f, a2 = 0.f, a3 = 0.f;
#pragma unroll
            for (int j = 0; j < 8; ++j) {
                uint4 wv = w1q[(wave * 8 + j) * 64 + lane];
                a0 = fdot2u(hp[j], wv.x, a0); a1 = fdot2u(hp[j], wv.y, a1);
                a2 = fdot2u(hp[j], wv.z, a2); a3 = fdot2u(hp[j], wv.w, a3);
            }
            *(f32x4*)(part + wave * 256 + 4 * lane) = (f32x4){a0, a1, a2, a3};
        }
        // prefetch L2 weights (i=0..3) across the barriers
        uint4 w2p0 = g2q[(wave * 16 + 0) * 128 + 2 * lane];
        uint4 w2p1 = g2q[(wave * 16 + 0) * 128 + 2 * lane + 1];
        uint4 w2p2 = g2q[(wave * 16 + 1) * 128 + 2 * lane];
        uint4 w2p3 = g2q[(wave * 16 + 1) * 128 + 2 * lane + 1];
        uint4 w2p4 = g2q[(wave * 16 + 2) * 128 + 2 * lane];
        uint4 w2p5 = g2q[(wave * 16 + 2) * 128 + 2 * lane + 1];
        uint4 w2p6 = g2q[(wave * 16 + 3) * 128 + 2 * lane];
        uint4 w2p7 = g2q[(wave * 16 + 3) * 128 + 2 * lane + 1];
        __syncthreads();
        if (t < 128) {
            const float2* p2 = (const float2*)part;
            float z0 = b1p.x, z1 = b1p.y;
#pragma unroll
            for (int q = 0; q < 8; ++q) { float2 pv = p2[q * 128 + t]; z0 += pv.x; z1 += pv.y; }
            h1q[t] = packh(fast_tanh(z0), fast_tanh(z1));
        }
        __syncthreads();
        // ---- L2: h1(128kp) -> h2(512c). streamed. wave=k-slice(16kp), lane=8 cols ----
        {
            uint4 ha0 = h1q4[wave * 4], ha1 = h1q4[wave * 4 + 1];
            uint4 ha2 = h1q4[wave * 4 + 2], ha3 = h1q4[wave * 4 + 3];
            unsigned int hp[16] = {ha0.x, ha0.y, ha0.z, ha0.w, ha1.x, ha1.y, ha1.z, ha1.w,
                                   ha2.x, ha2.y, ha2.z, ha2.w, ha3.x, ha3.y, ha3.z, ha3.w};
            float a0 = 0.f, a1 = 0.f, a2 = 0.f, a3 = 0.f;
            float a4 = 0.f, a5 = 0.f, a6 = 0.f, a7 = 0.f;
#pragma unroll
            for (int i = 0; i < 16; ++i) {
                uint4 wv0, wv1;
                if (i == 0)      { wv0 = w2p0; wv1 = w2p1; }
                else if (i == 1) { wv0 = w2p2; wv1 = w2p3; }
                else if (i == 2) { wv0 = w2p4; wv1 = w2p5; }
                else if (i == 3) { wv0 = w2p6; wv1 = w2p7; }
                else {
                    wv0 = g2q[(wave * 16 + i) * 128 + 2 * lane];
                    wv1 = g2q[(wave * 16 + i) * 128 + 2 * lane + 1];
                }
                a0 = fdot2u(hp[i], wv0.x, a0); a1 = fdot2u(hp[i], wv0.y, a1);
                a2 = fdot2u(hp[i], wv0.z, a2); a3 = fdot2u(hp[i], wv0.w, a3);
                a4 = fdot2u(hp[i], wv1.x, a4); a5 = fdot2u(hp[i], wv1.y, a5);
                a6 = fdot2u(hp[i], wv1.z, a6); a7 = fdot2u(hp[i], wv1.w, a7);
            }
            *(f32x4*)(part + wave * 512 + 8 * lane)     = (f32x4){a0, a1, a2, a3};
            *(f32x4*)(part + wave * 512 + 8 * lane + 4) = (f32x4){a4, a5, a6, a7};
        }
        // prefetch L3 weights (i=0..3)
        uint4 w3p0 = g3q[(kq16 * 16 + 0) * 64 + 2 * g32];
        uint4 w3p1 = g3q[(kq16 * 16 + 0) * 64 + 2 * g32 + 1];
        uint4 w3p2 = g3q[(kq16 * 16 + 1) * 64 + 2 * g32];
        uint4 w3p3 = g3q[(kq16 * 16 + 1) * 64 + 2 * g32 + 1];
        uint4 w3p4 = g3q[(kq16 * 16 + 2) * 64 + 2 * g32];
        uint4 w3p5 = g3q[(kq16 * 16 + 2) * 64 + 2 * g32 + 1];
        uint4 w3p6 = g3q[(kq16 * 16 + 3) * 64 + 2 * g32];
        uint4 w3p7 = g3q[(kq16 * 16 + 3) * 64 + 2 * g32 + 1];
        __syncthreads();
        if (t < 256) {
            const float2* p2 = (const float2*)part;
            float z0 = b2p.x, z1 = b2p.y;
#pragma unroll
            for (int q = 0; q < 8; ++q) { float2 pv = p2[q * 256 + t]; z0 += pv.x; z1 += pv.y; }
            h2q[t] = packh(fast_tanh(z0), fast_tanh(z1));
        }
        __syncthreads();
        // ---- L3: h2(256kp) -> h3(256c). streamed. kq16=k-slice(16kp), g32=8 cols ----
        {
            uint4 ha0 = h2q4[kq16 * 4], ha1 = h2q4[kq16 * 4 + 1];
            uint4 ha2 = h2q4[kq16 * 4 + 2], ha3 = h2q4[kq16 * 4 + 3];
            unsigned int hp[16] = {ha0.x, ha0.y, ha0.z, ha0.w, ha1.x, ha1.y, ha1.z, ha1.w,
                                   ha2.x, ha2.y, ha2.z, ha2.w, ha3.x, ha3.y, ha3.z, ha3.w};
            float a0 = 0.f, a1 = 0.f, a2 = 0.f, a3 = 0.f;
            float a4 = 0.f, a5 = 0.f, a6 = 0.f, a7 = 0.f;
#pragma unroll
            for (int i = 0; i < 16; ++i) {
                uint4 wv0, wv1;
                if (i == 0)      { wv0 = w3p0; wv1 = w3p1; }
                else if (i == 1) { wv0 = w3p2; wv1 = w3p3; }
                else if (i == 2) { wv0 = w3p4; wv1 = w3p5; }
                else if (i == 3) { wv0 = w3p6; wv1 = w3p7; }
                else {
                    wv0 = g3q[(kq16 * 16 + i) * 64 + 2 * g32];
                    wv1 = g3q[(kq16 * 16 + i) * 64 + 2 * g32 + 1];
                }
                a0 = fdot2u(hp[i], wv0.x, a0); a1 = fdot2u(hp[i], wv0.y, a1);
                a2 = fdot2u(hp[i], wv0.z, a2); a3 = fdot2u(hp[i], wv0.w, a3);
                a4 = fdot2u(hp[i], wv1.x, a4); a5 = fdot2u(hp[i], wv1.y, a5);
                a6 = fdot2u(hp[i], wv1.z, a6); a7 = fdot2u(hp[i], wv1.w, a7);
            }
            *(f32x4*)(part + kq16 * 256 + 8 * g32)     = (f32x4){a0, a1, a2, a3};
            *(f32x4*)(part + kq16 * 256 + 8 * g32 + 4) = (f32x4){a4, a5, a6, a7};
        }
        __syncthreads();
        if (t < 128) {
            const float2* p2 = (const float2*)part;
            float z0 = b3p.x, z1 = b3p.y;
#pragma unroll
            for (int q = 0; q < 16; ++q) { float2 pv = p2[q * 128 + t]; z0 += pv.x; z1 += pv.y; }
            h3q[t] = packh(fast_tanh(z0), fast_tanh(z1));
        }
        __syncthreads();
        // ---- L4: h3(128kp) -> k(128c). W4 LDS. kq16=k-slice(8kp), g32=4 cols ----
        {
            uint4 ha0 = h3q4[kq16 * 2], ha1 = h3q4[kq16 * 2 + 1];
            unsigned int hp[8] = {ha0.x, ha0.y, ha0.z, ha0.w, ha1.x, ha1.y, ha1.z, ha1.w};
            float a0 = 0.f, a1 = 0.f, a2 = 0.f, a3 = 0.f;
#pragma unroll
            for (int i = 0; i < 8; ++i) {
                uint4 wv = w4q[(kq16 * 8 + i) * 32 + g32];
                a0 = fdot2u(hp[i], wv.x, a0); a1 = fdot2u(hp[i], wv.y, a1);
                a2 = fdot2u(hp[i], wv.z, a2); a3 = fdot2u(hp[i], wv.w, a3);
            }
            *(f32x4*)(part + kq16 * 128 + 4 * g32) = (f32x4){a0, a1, a2, a3};
        }
        __syncthreads();
        if (t < 64) {
            const float2* p2 = (const float2*)part;
            float k0 = b4p.x, k1 = b4p.y;
#pragma unroll
            for (int q = 0; q < 16; ++q) { float2 pv = p2[q * 64 + t]; k0 += pv.x; k1 += pv.y; }
            float wB = (s == 0 || s == 3) ? dt * (1.f / 6.f) : dt * (1.f / 3.f);
            xa0 += wB * k0; xa1 += wB * k1;
            float v0, v1;
            if (s < 3) {
                float cc = (s == 2) ? dt : 0.5f * dt;
                v0 = xs0 + cc * k0; v1 = xs1 + cc * k1;
            } else {
                xs0 = xa0; xs1 = xa1; v0 = xs0; v1 = xs1;
            }
            vq[t] = packh(v0, v1);
        }
        __syncthreads();
    }
    if (t < 64) {
        float2 ov; ov.x = xs0; ov.y = xs1;
        ((float2*)branch)[blockIdx.x * 64 + t] = ov;
    }
}

// ---------------------------------------------------------------------------
// K2: fused trunk + combine. M=64 rows/WG, 1024 thr (16 waves), 4x B-reuse.
// ---------------------------------------------------------------------------
__device__ __forceinline__ int swz(int row, int byte_in_row) {
    return (row * 1024 + byte_in_row) ^ ((row & 7) << 4);
}

extern __shared__ char tk_smem[];

__global__ __launch_bounds__(1024, 4) void trunk_kernel(
    const float* __restrict__ coords,
    const float* __restrict__ tW1, const float* __restrict__ tb1,
    const unsigned short* __restrict__ tW2T, const float* __restrict__ tb2,
    const unsigned short* __restrict__ tW3T, const float* __restrict__ tb3,
    const float* __restrict__ oW, const float* __restrict__ ob,
    const float* __restrict__ branch, float* __restrict__ out) {
    const int t = threadIdx.x;
    const int blk = blockIdx.x;
    const int b = blk >> 5;
    const int p0 = (blk & 31) * 64;

    float* coordsLds = (float*)(tk_smem + 131072);
    float* bwp = (float*)(tk_smem + 132096);
    if (t < 256) coordsLds[t] = coords[(b * 2048 + p0) * 4 + t];
    else if (t < 384) bwp[t - 256] = branch[b * 128 + (t - 256)] * oW[t - 256];
    __syncthreads();

    {
        const int r = t & 63, cs = t >> 6;
        const float c0 = coordsLds[r * 4 + 0], c1 = coordsLds[r * 4 + 1];
        const float c2 = coordsLds[r * 4 + 2], c3 = coordsLds[r * 4 + 3];
#pragma unroll
        for (int i = 0; i < 32; i += 2) {
            int c = cs * 32 + i;
            float v0 = fmaxf(c0 * tW1[c] + c1 * tW1[512 + c] + c2 * tW1[1024 + c] +
                                 c3 * tW1[1536 + c] + tb1[c], 0.f);
            float v1 = fmaxf(c0 * tW1[c + 1] + c1 * tW1[512 + c + 1] + c2 * tW1[1024 + c + 1] +
                                 c3 * tW1[1536 + c + 1] + tb1[c + 1], 0.f);
            *(unsigned int*)(tk_smem + swz(r, c * 2)) =
                (unsigned int)f2bf(v0) | ((unsigned int)f2bf(v1) << 16);
        }
    }
    __syncthreads();

    const int w = t >> 6, l = t & 63;
    const int lrow = l & 15, lk8 = (l >> 4) * 8;

    {
        const int colbase = w * 32;
        f32x4 acc[4][2];
#pragma unroll
        for (int nt = 0; nt < 2; ++nt) {
            float bias = tb2[colbase + nt * 16 + lrow];
#pragma unroll
            for (int rt = 0; rt < 4; ++rt) acc[rt][nt] = (f32x4){bias, bias, bias, bias};
        }
        for (int ksI = 0; ksI < 16; ++ksI) {
            int kb = ksI * 32 + lk8;
            bf16x8 af[4];
#pragma unroll
            for (int rt = 0; rt < 4; ++rt)
                af[rt] = *(const bf16x8*)(tk_smem + swz(rt * 16 + lrow, kb * 2));
#pragma unroll
            for (int nt = 0; nt < 2; ++nt) {
                bf16x8 bfr = *(const bf16x8*)(tW2T + (colbase + nt * 16 + lrow) * 512 + kb);
#pragma unroll
                for (int rt = 0; rt < 4; ++rt)
                    acc[rt][nt] = __builtin_amdgcn_mfma_f32_16x16x32_bf16(af[rt], bfr, acc[rt][nt], 0, 0, 0);
            }
        }
#pragma unroll
        for (int nt = 0; nt < 2; ++nt) {
            int col = colbase + nt * 16 + lrow;
#pragma unroll
            for (int rt = 0; rt < 4; ++rt)
#pragma unroll
                for (int i = 0; i < 4; ++i) {
                    int rw = rt * 16 + (l >> 4) * 4 + i;
                    *(unsigned short*)(tk_smem + 65536 + swz(rw, col * 2)) =
                        f2bf(fmaxf(acc[rt][nt][i], 0.f));
                }
        }
    }
    __syncthreads();

    {
        float* h3p = (float*)tk_smem;
        if (w < 8) {
            const int colbase = w * 16;
            f32x4 acc3[4];
            float bias = tb3[colbase + lrow];
#pragma unroll
            for (int rt = 0; rt < 4; ++rt) acc3[rt] = (f32x4){bias, bias, bias, bias};
            for (int ksI = 0; ksI < 16; ++ksI) {
                int kb = ksI * 32 + lk8;
                bf16x8 bfr = *(const bf16x8*)(tW3T + (colbase + lrow) * 512 + kb);
#pragma unroll
                for (int rt = 0; rt < 4; ++rt) {
                    bf16x8 af = *(const bf16x8*)(tk_smem + 65536 + swz(rt * 16 + lrow, kb * 2));
                    acc3[rt] = __builtin_amdgcn_mfma_f32_16x16x32_bf16(af, bfr, acc3[rt], 0, 0, 0);
                }
            }
            __syncthreads();
#pragma unroll
            for (int rt = 0; rt < 4; ++rt)
#pragma unroll
                for (int i = 0; i < 4; ++i) {
                    int rw = rt * 16 + (l >> 4) * 4 + i;
                    h3p[rw * 132 + colbase + lrow] = fmaxf(acc3[rt][i], 0.f);
                }
        } else {
            __syncthreads();
        }
    }
    __syncthreads();

    {
        const float* h3p = (const float*)tk_smem;
        const int p = t >> 4, seg = t & 15;
        float s = 0.f;
#pragma unroll
        for (int i = 0; i < 8; ++i) {
            int d = seg * 8 + i;
            s += h3p[p * 132 + d] * bwp[d];
        }
        s += __shfl_down(s, 8, 16);
        s += __shfl_down(s, 4, 16);
        s += __shfl_down(s, 2, 16);
        s += __shfl_down(s, 1, 16);
        if (seg == 0) out[b * 2048 + p0 + p] = s + ob[0];
    }
}

// ---------------------------------------------------------------------------
extern "C" void kernel_launch(void* const* d_in, const int* in_sizes, int n_in,
                              void* d_out, int out_size, void* d_ws, size_t ws_size,
                              hipStream_t stream) {
    const float* parameter = (const float*)d_in[0];
    const float* coords    = (const float*)d_in[1];
    const float* bW1 = (const float*)d_in[2];  const float* bb1 = (const float*)d_in[3];
    const float* bW2 = (const float*)d_in[4];  const float* bb2 = (const float*)d_in[5];
    const float* bW3 = (const float*)d_in[6];  const float* bb3 = (const float*)d_in[7];
    const float* bW4 = (const float*)d_in[8];  const float* bb4 = (const float*)d_in[9];
    const float* tW1 = (const float*)d_in[10]; const float* tb1 = (const float*)d_in[11];
    const float* tW2 = (const float*)d_in[12]; const float* tb2 = (const float*)d_in[13];
    const float* tW3 = (const float*)d_in[14]; const float* tb3 = (const float*)d_in[15];
    const float* oW  = (const float*)d_in[16]; const float* ob  = (const float*)d_in[17];

    char* ws = (char*)d_ws;
    unsigned short* tW2T = (unsigned short*)(ws);             // 524288
    unsigned short* tW3T = (unsigned short*)(ws + 524288);    // 131072
    unsigned int*   W1u  = (unsigned int*)(ws + 655360);      // 65536
    unsigned int*   W2u  = (unsigned int*)(ws + 720896);      // 262144
    unsigned int*   W3u  = (unsigned int*)(ws + 983040);      // 262144
    unsigned int*   W4u  = (unsigned int*)(ws + 1245184);     // 65536
    float* branch        = (float*)(ws + 1310720);            // 32768
    float* out = (float*)d_out;

    hipLaunchKernelGGL(convert_kernel, dim3(1920), dim3(256), 0, stream,
                       tW2, tW3, bW1, bW2, bW3, bW4,
                       tW2T, tW3T, W1u, W2u, W3u, W4u);

    hipFuncSetAttribute(reinterpret_cast<const void*>(&ode_kernel),
                        hipFuncAttributeMaxDynamicSharedMemorySize, 149760);
    hipLaunchKernelGGL(ode_kernel, dim3(64), dim3(512), 149760, stream,
                       parameter, W1u, bb1, W2u, bb2, W3u, bb3, W4u, bb4, branch);

    hipFuncSetAttribute(reinterpret_cast<const void*>(&trunk_kernel),
                        hipFuncAttributeMaxDynamicSharedMemorySize, 132608);
    hipLaunchKernelGGL(trunk_kernel, dim3(2048), dim3(1024), 132608, stream,
                       coords, tW1, tb1, tW2T, tb2, tW3T, tb3, oW, ob, branch, out);
}

// Round 5
// 864.421 us; speedup vs baseline: 1.9908x; 1.1468x over previous
//
#include <hip/hip_runtime.h>
#include <hip/hip_bf16.h>

using bf16x8 = __attribute__((ext_vector_type(8))) short;
using f32x4  = __attribute__((ext_vector_type(4))) float;
using f16x2  = __attribute__((ext_vector_type(2))) _Float16;

#define ODE_NSTEP 32  // RK4 x32 validated (absmax identical to fp32 RK45x49)

__device__ __forceinline__ unsigned short f2bf(float f) {
    unsigned int u = __float_as_uint(f);
    return (unsigned short)((u + 0x7fffu + ((u >> 16) & 1u)) >> 16);
}
__device__ __forceinline__ float bf2f(unsigned short s) {
    return __uint_as_float(((unsigned int)s) << 16);
}
__device__ __forceinline__ unsigned short f2h(float f) {
    _Float16 h = (_Float16)f;
    return __builtin_bit_cast(unsigned short, h);
}
__device__ __forceinline__ unsigned int packh(float lo, float hi) {
    return (unsigned int)f2h(lo) | ((unsigned int)f2h(hi) << 16);
}
__device__ __forceinline__ float fdot2u(unsigned int a, unsigned int b, float c) {
#if __has_builtin(__builtin_amdgcn_fdot2)
    return __builtin_amdgcn_fdot2(__builtin_bit_cast(f16x2, a),
                                  __builtin_bit_cast(f16x2, b), c, false);
#else
    f16x2 av = __builtin_bit_cast(f16x2, a), bv = __builtin_bit_cast(f16x2, b);
    return c + (float)av.x * (float)bv.x + (float)av.y * (float)bv.y;
#endif
}
__device__ __forceinline__ float fast_tanh(float xx) {
    float a = __expf(-2.f * fabsf(xx));
    float r = (1.f - a) / (1.f + a);
    return copysignf(r, xx);
}

// ---------------------------------------------------------------------------
// K0: weight repack (identical to round 4).
// ---------------------------------------------------------------------------
__global__ void convert_kernel(const float* __restrict__ tW2, const float* __restrict__ tW3,
                               const float* __restrict__ bW1, const float* __restrict__ bW2,
                               const float* __restrict__ bW3, const float* __restrict__ bW4,
                               unsigned short* __restrict__ tW2T, unsigned short* __restrict__ tW3T,
                               unsigned int* __restrict__ W1u, unsigned int* __restrict__ W2u,
                               unsigned int* __restrict__ W3u, unsigned int* __restrict__ W4u) {
    int idx = blockIdx.x * blockDim.x + threadIdx.x;
    if (idx < 262144) {
        int col = idx >> 9, k = idx & 511;
        tW2T[idx] = f2bf(tW2[k * 512 + col]);
    } else if (idx < 327680) {
        int i = idx - 262144, col = i >> 9, k = i & 511;
        tW3T[i] = f2bf(tW3[k * 128 + col]);
    } else if (idx < 344064) {
        int i = idx - 327680, kp = i >> 8, c = i & 255;
        W1u[i] = packh(bW1[(2 * kp) * 256 + c], bW1[(2 * kp + 1) * 256 + c]);
    } else if (idx < 409600) {
        int i = idx - 344064, kp = i >> 9, c = i & 511;
        W2u[i] = packh(bW2[(2 * kp) * 512 + c], bW2[(2 * kp + 1) * 512 + c]);
    } else if (idx < 475136) {
        int i = idx - 409600, kp = i >> 8, c = i & 255;
        W3u[i] = packh(bW3[(2 * kp) * 256 + c], bW3[(2 * kp + 1) * 256 + c]);
    } else if (idx < 491520) {
        int i = idx - 475136, kp = i >> 7, c = i & 127;
        W4u[i] = packh(bW4[(2 * kp) * 128 + c], bW4[(2 * kp + 1) * 128 + c]);
    }
}

// ---------------------------------------------------------------------------
// ODE body (blocks 0..63). Round-4 structure; L2 now W2-in-registers full-K.
// LDS map: w1@0 64K | w4@65536 64K | part@131072 16K | vq@147456 | h1q@147712
//          h2h@148224 | h3q@149248 .. 149760
// ---------------------------------------------------------------------------
__device__ __forceinline__ void ode_body(
    char* smem, int row,
    const float* __restrict__ x0,
    const unsigned int* __restrict__ gW1, const float* __restrict__ bb1,
    const unsigned int* __restrict__ gW2, const float* __restrict__ bb2,
    const unsigned int* __restrict__ gW3, const float* __restrict__ bb3,
    const unsigned int* __restrict__ gW4, const float* __restrict__ bb4,
    float* __restrict__ branch) {
    unsigned int* w1  = (unsigned int*)smem;
    unsigned int* w4  = (unsigned int*)(smem + 65536);
    float*        part = (float*)(smem + 131072);
    unsigned int* vq  = (unsigned int*)(smem + 147456);
    unsigned int* h1q = (unsigned int*)(smem + 147712);
    unsigned short* h2h = (unsigned short*)(smem + 148224);
    unsigned int* h3q = (unsigned int*)(smem + 149248);

    const int t = threadIdx.x;
    const int lane = t & 63, wave = t >> 6;
    const int kq16 = t >> 5, g32 = t & 31;

    {   // stage resident weights
        const uint4* s1 = (const uint4*)gW1; uint4* d1 = (uint4*)w1;
#pragma unroll
        for (int i = 0; i < 8; ++i) d1[t + i * 512] = s1[t + i * 512];
        const uint4* s4 = (const uint4*)gW4; uint4* d4 = (uint4*)w4;
#pragma unroll
        for (int i = 0; i < 8; ++i) d4[t + i * 512] = s4[t + i * 512];
    }
    // W2 -> registers: thread t owns output col t; w2r[j] = kps 4j..4j+3 (f16 pairs)
    uint4 w2r[32];
#pragma unroll
    for (int j = 0; j < 32; ++j) {
        w2r[j].x = gW2[(4 * j + 0) * 512 + t];
        w2r[j].y = gW2[(4 * j + 1) * 512 + t];
        w2r[j].z = gW2[(4 * j + 2) * 512 + t];
        w2r[j].w = gW2[(4 * j + 3) * 512 + t];
    }
    float2 b1p = make_float2(0.f, 0.f), b3p = b1p, b4p = b1p;
    if (t < 128) b1p = ((const float2*)bb1)[t];
    const float b2s = bb2[t];
    if (t < 128) b3p = ((const float2*)bb3)[t];
    if (t < 64)  b4p = ((const float2*)bb4)[t];
    float xs0 = 0.f, xs1 = 0.f, xa0 = 0.f, xa1 = 0.f;
    if (t < 64) {
        float2 xv = ((const float2*)x0)[row * 64 + t];
        xs0 = xv.x; xs1 = xv.y; xa0 = xs0; xa1 = xs1;
        vq[t] = packh(xs0, xs1);
    }
    __syncthreads();

    const float dt = 1.0f / (float)ODE_NSTEP;
    const uint4* vq4  = (const uint4*)vq;
    const uint4* h1q4 = (const uint4*)h1q;
    const uint4* h2q4 = (const uint4*)h2h;
    const uint4* h3q4 = (const uint4*)h3q;
    const uint4* w1q = (const uint4*)w1;
    const uint4* w4q = (const uint4*)w4;
    const uint4* g3q = (const uint4*)gW3;

    for (int it = 0; it < ODE_NSTEP * 4; ++it) {
        const int s = it & 3;
        // prefetch L3 weights (i=0..3) at top: retire under L1+L2 compute
        uint4 w3p0 = g3q[(kq16 * 16 + 0) * 64 + 2 * g32];
        uint4 w3p1 = g3q[(kq16 * 16 + 0) * 64 + 2 * g32 + 1];
        uint4 w3p2 = g3q[(kq16 * 16 + 1) * 64 + 2 * g32];
        uint4 w3p3 = g3q[(kq16 * 16 + 1) * 64 + 2 * g32 + 1];
        uint4 w3p4 = g3q[(kq16 * 16 + 2) * 64 + 2 * g32];
        uint4 w3p5 = g3q[(kq16 * 16 + 2) * 64 + 2 * g32 + 1];
        uint4 w3p6 = g3q[(kq16 * 16 + 3) * 64 + 2 * g32];
        uint4 w3p7 = g3q[(kq16 * 16 + 3) * 64 + 2 * g32 + 1];
        // ---- L1: v(64kp) -> h1(256c). W1 LDS. wave=8kp slice, lane=4 cols ----
        {
            uint4 va = vq4[wave * 2], vb = vq4[wave * 2 + 1];
            unsigned int hp[8] = {va.x, va.y, va.z, va.w, vb.x, vb.y, vb.z, vb.w};
            float a0 = 0.f, a1 = 0.f, a2 = 0.f, a3 = 0.f;
#pragma unroll
            for (int j = 0; j < 8; ++j) {
                uint4 wv = w1q[(wave * 8 + j) * 64 + lane];
                a0 = fdot2u(hp[j], wv.x, a0); a1 = fdot2u(hp[j], wv.y, a1);
                a2 = fdot2u(hp[j], wv.z, a2); a3 = fdot2u(hp[j], wv.w, a3);
            }
            *(f32x4*)(part + wave * 256 + 4 * lane) = (f32x4){a0, a1, a2, a3};
        }
        __syncthreads();
        if (t < 128) {
            const float2* p2 = (const float2*)part;
            float z0 = b1p.x, z1 = b1p.y;
#pragma unroll
            for (int q = 0; q < 8; ++q) { float2 pv = p2[q * 128 + t]; z0 += pv.x; z1 += pv.y; }
            h1q[t] = packh(fast_tanh(z0), fast_tanh(z1));
        }
        __syncthreads();
        // ---- L2: h1(128kp) -> h2(512c). W2 in regs, full-K per thread ----
        {
            float a0 = b2s, a1 = 0.f, a2 = 0.f, a3 = 0.f;
#pragma unroll
            for (int j = 0; j < 32; ++j) {
                uint4 hb = h1q4[j];  // wave-uniform broadcast
                uint4 wv = w2r[j];
                a0 = fdot2u(hb.x, wv.x, a0); a1 = fdot2u(hb.y, wv.y, a1);
                a2 = fdot2u(hb.z, wv.z, a2); a3 = fdot2u(hb.w, wv.w, a3);
            }
            h2h[t] = f2h(fast_tanh((a0 + a1) + (a2 + a3)));
        }
        __syncthreads();
        // ---- L3: h2(256kp) -> h3(256c). streamed. kq16=16kp slice, g32=8 cols ----
        {
            uint4 ha0 = h2q4[kq16 * 4], ha1 = h2q4[kq16 * 4 + 1];
            uint4 ha2 = h2q4[kq16 * 4 + 2], ha3 = h2q4[kq16 * 4 + 3];
            unsigned int hp[16] = {ha0.x, ha0.y, ha0.z, ha0.w, ha1.x, ha1.y, ha1.z, ha1.w,
                                   ha2.x, ha2.y, ha2.z, ha2.w, ha3.x, ha3.y, ha3.z, ha3.w};
            float a0 = 0.f, a1 = 0.f, a2 = 0.f, a3 = 0.f;
            float a4 = 0.f, a5 = 0.f, a6 = 0.f, a7 = 0.f;
#pragma unroll
            for (int i = 0; i < 16; ++i) {
                uint4 wv0, wv1;
                if (i == 0)      { wv0 = w3p0; wv1 = w3p1; }
                else if (i == 1) { wv0 = w3p2; wv1 = w3p3; }
                else if (i == 2) { wv0 = w3p4; wv1 = w3p5; }
                else if (i == 3) { wv0 = w3p6; wv1 = w3p7; }
                else {
                    wv0 = g3q[(kq16 * 16 + i) * 64 + 2 * g32];
                    wv1 = g3q[(kq16 * 16 + i) * 64 + 2 * g32 + 1];
                }
                a0 = fdot2u(hp[i], wv0.x, a0); a1 = fdot2u(hp[i], wv0.y, a1);
                a2 = fdot2u(hp[i], wv0.z, a2); a3 = fdot2u(hp[i], wv0.w, a3);
                a4 = fdot2u(hp[i], wv1.x, a4); a5 = fdot2u(hp[i], wv1.y, a5);
                a6 = fdot2u(hp[i], wv1.z, a6); a7 = fdot2u(hp[i], wv1.w, a7);
            }
            *(f32x4*)(part + kq16 * 256 + 8 * g32)     = (f32x4){a0, a1, a2, a3};
            *(f32x4*)(part + kq16 * 256 + 8 * g32 + 4) = (f32x4){a4, a5, a6, a7};
        }
        __syncthreads();
        if (t < 128) {
            const float2* p2 = (const float2*)part;
            float z0 = b3p.x, z1 = b3p.y;
#pragma unroll
            for (int q = 0; q < 16; ++q) { float2 pv = p2[q * 128 + t]; z0 += pv.x; z1 += pv.y; }
            h3q[t] = packh(fast_tanh(z0), fast_tanh(z1));
        }
        __syncthreads();
        // ---- L4: h3(128kp) -> k(128c). W4 LDS. kq16=8kp slice, g32=4 cols ----
        {
            uint4 ha0 = h3q4[kq16 * 2], ha1 = h3q4[kq16 * 2 + 1];
            unsigned int hp[8] = {ha0.x, ha0.y, ha0.z, ha0.w, ha1.x, ha1.y, ha1.z, ha1.w};
            float a0 = 0.f, a1 = 0.f, a2 = 0.f, a3 = 0.f;
#pragma unroll
            for (int i = 0; i < 8; ++i) {
                uint4 wv = w4q[(kq16 * 8 + i) * 32 + g32];
                a0 = fdot2u(hp[i], wv.x, a0); a1 = fdot2u(hp[i], wv.y, a1);
                a2 = fdot2u(hp[i], wv.z, a2); a3 = fdot2u(hp[i], wv.w, a3);
            }
            *(f32x4*)(part + kq16 * 128 + 4 * g32) = (f32x4){a0, a1, a2, a3};
        }
        __syncthreads();
        if (t < 64) {
            const float2* p2 = (const float2*)part;
            float k0 = b4p.x, k1 = b4p.y;
#pragma unroll
            for (int q = 0; q < 16; ++q) { float2 pv = p2[q * 64 + t]; k0 += pv.x; k1 += pv.y; }
            float wB = (s == 0 || s == 3) ? dt * (1.f / 6.f) : dt * (1.f / 3.f);
            xa0 += wB * k0; xa1 += wB * k1;
            float v0, v1;
            if (s < 3) {
                float cc = (s == 2) ? dt : 0.5f * dt;
                v0 = xs0 + cc * k0; v1 = xs1 + cc * k1;
            } else {
                xs0 = xa0; xs1 = xa1; v0 = xs0; v1 = xs1;
            }
            vq[t] = packh(v0, v1);
        }
        __syncthreads();
    }
    if (t < 64) {
        float2 ov; ov.x = xs0; ov.y = xs1;
        ((float2*)branch)[row * 64 + t] = ov;
    }
}

// ---------------------------------------------------------------------------
// Trunk body (512 thr, M=64 rows, 8 waves x 64 cols, B double-buffered).
// serialTail=false: write h3 bf16 to h3T (combine done later).
// serialTail=true : combine inline with branch (fallback path).
// ---------------------------------------------------------------------------
__device__ __forceinline__ int swz(int row, int byte_in_row) {
    return (row * 1024 + byte_in_row) ^ ((row & 7) << 4);
}

__device__ __forceinline__ void trunk_body(
    char* smem, int t2, bool serialTail,
    const float* __restrict__ coords,
    const float* __restrict__ tW1, const float* __restrict__ tb1,
    const unsigned short* __restrict__ tW2T, const float* __restrict__ tb2,
    const unsigned short* __restrict__ tW3T, const float* __restrict__ tb3,
    const float* __restrict__ oW, const float* __restrict__ ob,
    const float* __restrict__ branch, unsigned short* __restrict__ h3T,
    float* __restrict__ out) {
    const int t = threadIdx.x;
    const int b = t2 >> 5;
    const int p0 = (t2 & 31) * 64;

    float* coordsLds = (float*)(smem + 131072);
    float* bwp = (float*)(smem + 132096);
    if (t < 256) coordsLds[t] = coords[(b * 2048 + p0) * 4 + t];
    else if (serialTail && t < 384) bwp[t - 256] = branch[b * 128 + (t - 256)] * oW[t - 256];
    __syncthreads();

    // ---- L1: h1[64][512] = relu(coords @ tW1 + tb1) -> bf16 swizzled @0 ----
    {
        const int r = t & 63, cs = t >> 6;
        const float c0 = coordsLds[r * 4 + 0], c1 = coordsLds[r * 4 + 1];
        const float c2 = coordsLds[r * 4 + 2], c3 = coordsLds[r * 4 + 3];
#pragma unroll
        for (int i = 0; i < 64; i += 2) {
            int c = cs * 64 + i;
            float v0 = fmaxf(c0 * tW1[c] + c1 * tW1[512 + c] + c2 * tW1[1024 + c] +
                                 c3 * tW1[1536 + c] + tb1[c], 0.f);
            float v1 = fmaxf(c0 * tW1[c + 1] + c1 * tW1[512 + c + 1] + c2 * tW1[1024 + c + 1] +
                                 c3 * tW1[1536 + c + 1] + tb1[c + 1], 0.f);
            *(unsigned int*)(smem + swz(r, c * 2)) =
                (unsigned int)f2bf(v0) | ((unsigned int)f2bf(v1) << 16);
        }
    }
    __syncthreads();

    const int w = t >> 6, l = t & 63;
    const int lrow = l & 15, q = l >> 4, lk8 = q * 8;

    // ---- L2: h2[64][512]; wave w: cols w*64..+63 (4 nt), 4 rt row-tiles ----
    {
        const int colbase = w * 64;
        f32x4 acc[4][4];  // [rt][nt]
#pragma unroll
        for (int nt = 0; nt < 4; ++nt) {
            float bias = tb2[colbase + nt * 16 + lrow];
#pragma unroll
            for (int rt = 0; rt < 4; ++rt) acc[rt][nt] = (f32x4){bias, bias, bias, bias};
        }
        bf16x8 bc[4];
#pragma unroll
        for (int nt = 0; nt < 4; ++nt)
            bc[nt] = *(const bf16x8*)(tW2T + (colbase + nt * 16 + lrow) * 512 + lk8);
#pragma unroll 2
        for (int ksI = 0; ksI < 16; ++ksI) {
            const int kb = ksI * 32 + lk8;
            bf16x8 bn[4];
            if (ksI < 15) {
#pragma unroll
                for (int nt = 0; nt < 4; ++nt)
                    bn[nt] = *(const bf16x8*)(tW2T + (colbase + nt * 16 + lrow) * 512 + kb + 32);
            }
            bf16x8 af[4];
#pragma unroll
            for (int rt = 0; rt < 4; ++rt)
                af[rt] = *(const bf16x8*)(smem + swz(rt * 16 + lrow, kb * 2));
#pragma unroll
            for (int nt = 0; nt < 4; ++nt)
#pragma unroll
                for (int rt = 0; rt < 4; ++rt)
                    acc[rt][nt] = __builtin_amdgcn_mfma_f32_16x16x32_bf16(af[rt], bc[nt], acc[rt][nt], 0, 0, 0);
#pragma unroll
            for (int nt = 0; nt < 4; ++nt) bc[nt] = bn[nt];
        }
#pragma unroll
        for (int nt = 0; nt < 4; ++nt) {
            int col = colbase + nt * 16 + lrow;
#pragma unroll
            for (int rt = 0; rt < 4; ++rt)
#pragma unroll
                for (int i = 0; i < 4; ++i) {
                    int rw = rt * 16 + q * 4 + i;
                    *(unsigned short*)(smem + 65536 + swz(rw, col * 2)) =
                        f2bf(fmaxf(acc[rt][nt][i], 0.f));
                }
        }
    }
    __syncthreads();

    // ---- L3: h3[64][128]; wave w: cols w*16..+15 ----
    {
        const int col3 = w * 16 + lrow;
        f32x4 acc3[4];
        float bias = tb3[col3];
#pragma unroll
        for (int rt = 0; rt < 4; ++rt) acc3[rt] = (f32x4){bias, bias, bias, bias};
        bf16x8 bc3 = *(const bf16x8*)(tW3T + col3 * 512 + lk8);
#pragma unroll 2
        for (int ksI = 0; ksI < 16; ++ksI) {
            const int kb = ksI * 32 + lk8;
            bf16x8 bn3;
            if (ksI < 15) bn3 = *(const bf16x8*)(tW3T + col3 * 512 + kb + 32);
            bf16x8 af[4];
#pragma unroll
            for (int rt = 0; rt < 4; ++rt)
                af[rt] = *(const bf16x8*)(smem + 65536 + swz(rt * 16 + lrow, kb * 2));
#pragma unroll
            for (int rt = 0; rt < 4; ++rt)
                acc3[rt] = __builtin_amdgcn_mfma_f32_16x16x32_bf16(af[rt], bc3, acc3[rt], 0, 0, 0);
            bc3 = bn3;
        }
        if (!serialTail) {
            // store h3 bf16 to global: h3T[(b*128+d)*2048 + p]
#pragma unroll
            for (int rt = 0; rt < 4; ++rt) {
                float v0 = fmaxf(acc3[rt][0], 0.f), v1 = fmaxf(acc3[rt][1], 0.f);
                float v2 = fmaxf(acc3[rt][2], 0.f), v3 = fmaxf(acc3[rt][3], 0.f);
                uint2 pk;
                pk.x = (unsigned int)f2bf(v0) | ((unsigned int)f2bf(v1) << 16);
                pk.y = (unsigned int)f2bf(v2) | ((unsigned int)f2bf(v3) << 16);
                *(uint2*)(h3T + (unsigned long long)(b * 128 + col3) * 2048 +
                          p0 + rt * 16 + q * 4) = pk;
            }
        } else {
            float* h3p = (float*)smem;  // h1 region dead after L2 barrier
#pragma unroll
            for (int rt = 0; rt < 4; ++rt)
#pragma unroll
                for (int i = 0; i < 4; ++i) {
                    int rw = rt * 16 + q * 4 + i;
                    h3p[rw * 132 + col3] = fmaxf(acc3[rt][i], 0.f);
                }
            __syncthreads();
            const int p = t >> 3, seg = t & 7;
            float s = 0.f;
#pragma unroll
            for (int i = 0; i < 16; ++i) s += h3p[p * 132 + seg * 16 + i] * bwp[seg * 16 + i];
            s += __shfl_down(s, 4, 8);
            s += __shfl_down(s, 2, 8);
            s += __shfl_down(s, 1, 8);
            if (seg == 0) out[b * 2048 + p0 + p] = s + ob[0];
        }
    }
}

// ---------------------------------------------------------------------------
// Mega kernel: blocks < trunkOff run ODE rows, the rest run trunk tiles.
// ---------------------------------------------------------------------------
extern __shared__ char mega_smem[];

__global__ __launch_bounds__(512, 2) void mega_kernel(
    int trunkOff, int serialTail,
    const float* __restrict__ x0, const float* __restrict__ coords,
    const unsigned int* __restrict__ gW1, const float* __restrict__ bb1,
    const unsigned int* __restrict__ gW2, const float* __restrict__ bb2,
    const unsigned int* __restrict__ gW3, const float* __restrict__ bb3,
    const unsigned int* __restrict__ gW4, const float* __restrict__ bb4,
    const float* __restrict__ tW1, const float* __restrict__ tb1,
    const unsigned short* __restrict__ tW2T, const float* __restrict__ tb2,
    const unsigned short* __restrict__ tW3T, const float* __restrict__ tb3,
    const float* __restrict__ oW, const float* __restrict__ ob,
    float* __restrict__ branch, unsigned short* __restrict__ h3T,
    float* __restrict__ out) {
    if ((int)blockIdx.x < trunkOff) {
        ode_body(mega_smem, blockIdx.x, x0, gW1, bb1, gW2, bb2, gW3, bb3, gW4, bb4, branch);
    } else {
        trunk_body(mega_smem, blockIdx.x - trunkOff, serialTail != 0,
                   coords, tW1, tb1, tW2T, tb2, tW3T, tb3, oW, ob, branch, h3T, out);
    }
}

// ---------------------------------------------------------------------------
// Combine (fused mode): out[b][p] = sum_d h3T[b][d][p] * branch[b][d]*oW[d] + ob
// ---------------------------------------------------------------------------
__global__ __launch_bounds__(512) void combine_kernel(
    const float* __restrict__ branch, const float* __restrict__ oW,
    const float* __restrict__ ob, const unsigned short* __restrict__ h3T,
    float* __restrict__ out) {
    __shared__ float u[128];
    const int t = threadIdx.x;
    const int b = blockIdx.x >> 2;
    const int p = ((blockIdx.x & 3) << 9) + t;
    if (t < 128) u[t] = branch[b * 128 + t] * oW[t];
    __syncthreads();
    const unsigned short* hp = h3T + (unsigned long long)b * 128 * 2048 + p;
    float acc = ob[0];
#pragma unroll 8
    for (int d = 0; d < 128; ++d)
        acc = fmaf(bf2f(hp[d * 2048]), u[d], acc);
    out[b * 2048 + p] = acc;
}

// ---------------------------------------------------------------------------
extern "C" void kernel_launch(void* const* d_in, const int* in_sizes, int n_in,
                              void* d_out, int out_size, void* d_ws, size_t ws_size,
                              hipStream_t stream) {
    const float* parameter = (const float*)d_in[0];
    const float* coords    = (const float*)d_in[1];
    const float* bW1 = (const float*)d_in[2];  const float* bb1 = (const float*)d_in[3];
    const float* bW2 = (const float*)d_in[4];  const float* bb2 = (const float*)d_in[5];
    const float* bW3 = (const float*)d_in[6];  const float* bb3 = (const float*)d_in[7];
    const float* bW4 = (const float*)d_in[8];  const float* bb4 = (const float*)d_in[9];
    const float* tW1 = (const float*)d_in[10]; const float* tb1 = (const float*)d_in[11];
    const float* tW2 = (const float*)d_in[12]; const float* tb2 = (const float*)d_in[13];
    const float* tW3 = (const float*)d_in[14]; const float* tb3 = (const float*)d_in[15];
    const float* oW  = (const float*)d_in[16]; const float* ob  = (const float*)d_in[17];

    char* ws = (char*)d_ws;
    unsigned short* tW2T = (unsigned short*)(ws);             // 524288
    unsigned short* tW3T = (unsigned short*)(ws + 524288);    // 131072
    unsigned int*   W1u  = (unsigned int*)(ws + 655360);      // 65536
    unsigned int*   W2u  = (unsigned int*)(ws + 720896);      // 262144
    unsigned int*   W3u  = (unsigned int*)(ws + 983040);      // 262144
    unsigned int*   W4u  = (unsigned int*)(ws + 1245184);     // 65536
    float* branch        = (float*)(ws + 1310720);            // 32768
    unsigned short* h3T  = (unsigned short*)(ws + 2097152);   // 33554432
    float* out = (float*)d_out;

    const bool fused = (ws_size >= 35651584ull);

    hipLaunchKernelGGL(convert_kernel, dim3(1920), dim3(256), 0, stream,
                       tW2, tW3, bW1, bW2, bW3, bW4,
                       tW2T, tW3T, W1u, W2u, W3u, W4u);

    hipFuncSetAttribute(reinterpret_cast<const void*>(&mega_kernel),
                        hipFuncAttributeMaxDynamicSharedMemorySize, 149760);

    if (fused) {
        hipLaunchKernelGGL(mega_kernel, dim3(64 + 2048), dim3(512), 149760, stream,
                           64, 0, parameter, coords, W1u, bb1, W2u, bb2, W3u, bb3, W4u, bb4,
                           tW1, tb1, tW2T, tb2, tW3T, tb3, oW, ob, branch, h3T, out);
        hipLaunchKernelGGL(combine_kernel, dim3(256), dim3(512), 0, stream,
                           branch, oW, ob, h3T, out);
    } else {
        hipLaunchKernelGGL(mega_kernel, dim3(64), dim3(512), 149760, stream,
                           64, 1, parameter, coords, W1u, bb1, W2u, bb2, W3u, bb3, W4u, bb4,
                           tW1, tb1, tW2T, tb2, tW3T, tb3, oW, ob, branch, h3T, out);
        hipLaunchKernelGGL(mega_kernel, dim3(2048), dim3(512), 149760, stream,
                           0, 1, parameter, coords, W1u, bb1, W2u, bb2, W3u, bb3, W4u, bb4,
                           tW1, tb1, tW2T, tb2, tW3T, tb3, oW, ob, branch, h3T, out);
    }
}